// Round 5
// baseline (193.424 us; speedup 1.0000x reference)
//
#include <hip/hip_runtime.h>
#include <hip/hip_bf16.h>

typedef unsigned short u16;
typedef __bf16 bf16_t;
typedef bf16_t bf16x8 __attribute__((ext_vector_type(8)));
typedef float f32x4 __attribute__((ext_vector_type(4)));
typedef u16 u16x4 __attribute__((ext_vector_type(4)));
typedef u16 u16x8 __attribute__((ext_vector_type(8)));

#define S_LEN 4096
#define NH 8
#define HD 64
#define DM 512
#define NB 32

__device__ __forceinline__ u16 f2bf(float f) {
  unsigned int u = __builtin_bit_cast(unsigned int, f);
  u = (u + 0x7fff + ((u >> 16) & 1)) >> 16;  // RNE
  return (u16)u;
}
__device__ __forceinline__ float bf2f(u16 h) {
  unsigned int u = ((unsigned int)h) << 16;
  return __builtin_bit_cast(float, u);
}

#define GLDS16(gaddr, laddr)                                                  \
  __builtin_amdgcn_global_load_lds(                                           \
      (const __attribute__((address_space(1))) unsigned int*)(gaddr),         \
      (__attribute__((address_space(3))) unsigned int*)(laddr), 16, 0, 0)

// ---------------------------------------------------------------------------
// Weights: fp32 [K][N] -> bf16 transposed [N][K]; Wq scaled 1/8 (folds
// 1/sqrt(hd) into q so energy AND rel-bias are both scaled); Wo row-permuted
// (wrow = (k&63)*8 + (k>>6)) to fold transpose(0,2,3,1). grid (256,4) x 256.
// ---------------------------------------------------------------------------
__global__ __launch_bounds__(256) void conv_w(
    const float* __restrict__ Wq, const float* __restrict__ Wk,
    const float* __restrict__ Wv, const float* __restrict__ Wo,
    u16* __restrict__ WqT, u16* __restrict__ WkT, u16* __restrict__ WvT,
    u16* __restrict__ WoT) {
  const int z = blockIdx.y;
  const float* src = z == 0 ? Wq : (z == 1 ? Wk : (z == 2 ? Wv : Wo));
  u16* dst = z == 0 ? WqT : (z == 1 ? WkT : (z == 2 ? WvT : WoT));
  const float scl = (z == 0) ? 0.125f : 1.f;
  const int idx4 = blockIdx.x * 256 + threadIdx.x;
  const int nrow = idx4 >> 7;
  const int kbase = (idx4 & 127) * 4;
  u16x4 o;
#pragma unroll
  for (int j = 0; j < 4; ++j) {
    const int k = kbase + j;
    const int srow = (z == 3) ? ((k & 63) * 8 + (k >> 6)) : k;
    o[j] = f2bf(src[srow * DM + nrow] * scl);
  }
  *(u16x4*)(dst + nrow * DM + kbase) = o;
}

// ---------------------------------------------------------------------------
// rel_emb fp32 [8][129][64] -> bf16 [8][144][64] (row-padded; pad rows never
// read: idc <= 128). grid 129 x 128.
// ---------------------------------------------------------------------------
__global__ __launch_bounds__(128) void conv_rel(const float* __restrict__ rel,
                                                u16* __restrict__ relb) {
  const int e = (blockIdx.x * 128 + threadIdx.x) * 4;
  const int h = e / (129 * 64);
  const int rem = e - h * (129 * 64);
  const float4 v = *(const float4*)(rel + e);
  u16x4 o;
  o[0] = f2bf(v.x); o[1] = f2bf(v.y); o[2] = f2bf(v.z); o[3] = f2bf(v.w);
  *(u16x4*)(relb + (size_t)h * (144 * 64) + rem) = o;
}

// ---------------------------------------------------------------------------
// bf16 MFMA GEMM, 64x128 tile, BK=32, 4 waves (each 32x64), double-buffered
// prefetch-before-compute, swapped MFMA operands (D = C^T) for vectorized
// epilogue. Grid: proj 128x4x3 = 1536 blocks, out 128x4 = 512 blocks.
// MODE 1: A = raw fp32 (Q/K/V), conversion FUSED into reg-staging;
//         C scattered bf16 to (b,h,s,d); z picks tensor.
// MODE 2: A = attn-out bf16 in (b,h,s,d), k = h*64+d addressing, GLDS-staged;
//         C fp32 row-major.
// ---------------------------------------------------------------------------
template <int MODE>
__global__ __launch_bounds__(256, 4) void gemm_bf16(
    const float* __restrict__ Af0, const float* __restrict__ Af1,
    const float* __restrict__ Af2, const u16* __restrict__ Ab,
    const u16* __restrict__ B0, const u16* __restrict__ B1,
    const u16* __restrict__ B2, u16* __restrict__ C0, u16* __restrict__ C1,
    u16* __restrict__ C2, float* __restrict__ Cf) {
  __shared__ u16 As[2][64 * 32];   // 8 KB
  __shared__ u16 Bs[2][128 * 32];  // 16 KB

  const int z = blockIdx.z;
  const float* Af = (MODE == 1) ? (z == 0 ? Af0 : (z == 1 ? Af1 : Af2)) : 0;
  const u16* Bt = (MODE == 1) ? (z == 0 ? B0 : (z == 1 ? B1 : B2)) : B0;
  u16* Cb = (MODE == 1) ? (z == 0 ? C0 : (z == 1 ? C1 : C2)) : (u16*)0;

  const int tid = threadIdx.x;
  const int lane = tid & 63;
  const int w = tid >> 6;
  const int bm = blockIdx.x * 64;
  const int bn = blockIdx.y * 128;

  f32x4 acc[2][4];
#pragma unroll
  for (int mf = 0; mf < 2; ++mf)
#pragma unroll
    for (int nf = 0; nf < 4; ++nf) acc[mf][nf] = f32x4{0.f, 0.f, 0.f, 0.f};

  const int wr = w >> 1, wc = w & 1;
  const int lrow = lane & 15;
  const int lk = (lane >> 4) * 8;

  // staging thread mapping
  const int arow = tid >> 2;       // 0..63 (A row within tile)
  const int ac8 = (tid & 3) * 8;   // k offset
  const long aoff = (long)(bm + arow) * DM + ac8;  // MODE1 fp32 A base

  auto stageB = [&](int buf, int k0) {
#pragma unroll
    for (int c = 0; c < 2; ++c) {
      const int brow = bn + c * 64 + w * 16 + (lane >> 2);
      GLDS16(Bt + (long)brow * DM + k0 + (lane & 3) * 8,
             &Bs[buf][c * 2048 + w * 512]);
    }
  };
  auto stageA2 = [&](int buf, int k0) {  // MODE 2: bf16 (b,h,s,d) via GLDS
    const int r = bm + w * 16 + (lane >> 2);
    const int b = r >> 12, s = r & 4095;
    const int k = k0 + (lane & 3) * 8;
    GLDS16(Ab + ((long)((b * 8 + (k >> 6)) * 4096 + s)) * 64 + (k & 63),
           &As[buf][w * 512]);
  };
  auto writeA = [&](int buf, float4 x0, float4 x1) {  // MODE 1 pack+write
    u16x8 o;
    o[0] = f2bf(x0.x); o[1] = f2bf(x0.y); o[2] = f2bf(x0.z); o[3] = f2bf(x0.w);
    o[4] = f2bf(x1.x); o[5] = f2bf(x1.y); o[6] = f2bf(x1.z); o[7] = f2bf(x1.w);
    *(u16x8*)&As[buf][arow * 32 + ac8] = o;
  };

  auto compute = [&](int cur) {
    bf16x8 af[2], bfr[4];
#pragma unroll
    for (int mf = 0; mf < 2; ++mf)
      af[mf] = *(const bf16x8*)&As[cur][(wr * 32 + mf * 16 + lrow) * 32 + lk];
#pragma unroll
    for (int nf = 0; nf < 4; ++nf)
      bfr[nf] = *(const bf16x8*)&Bs[cur][(wc * 64 + nf * 16 + lrow) * 32 + lk];
#pragma unroll
    for (int mf = 0; mf < 2; ++mf)
#pragma unroll
      for (int nf = 0; nf < 4; ++nf)
        acc[mf][nf] = __builtin_amdgcn_mfma_f32_16x16x32_bf16(
            bfr[nf], af[mf], acc[mf][nf], 0, 0, 0);  // swapped: D = C^T
  };

  if constexpr (MODE == 1) {
    float4 c0 = *(const float4*)&Af[aoff];
    float4 c1 = *(const float4*)&Af[aoff + 4];
    stageB(0, 0);
    writeA(0, c0, c1);
    __syncthreads();
    for (int t = 0; t < 16; ++t) {
      const int cur = t & 1;
      float4 n0, n1;
      if (t < 15) {
        n0 = *(const float4*)&Af[aoff + (t + 1) * 32];      // fly during MFMA
        n1 = *(const float4*)&Af[aoff + (t + 1) * 32 + 4];
        stageB(cur ^ 1, (t + 1) * 32);
      }
      compute(cur);
      if (t < 15) writeA(cur ^ 1, n0, n1);
      __syncthreads();
    }
  } else {
    stageA2(0, 0);
    stageB(0, 0);
    __syncthreads();
    for (int t = 0; t < 16; ++t) {
      const int cur = t & 1;
      if (t < 15) {
        stageA2(cur ^ 1, (t + 1) * 32);
        stageB(cur ^ 1, (t + 1) * 32);
      }
      compute(cur);
      __syncthreads();
    }
  }

  // epilogue: D row = n-dim (lr4+j), col = m-dim (lc)
  const int lr4 = (lane >> 4) * 4;
  const int lc = lane & 15;
#pragma unroll
  for (int mf = 0; mf < 2; ++mf) {
    const int r = bm + wr * 32 + mf * 16 + lc;  // output row (s-dim)
    const int bi = r >> 12, s = r & 4095;
#pragma unroll
    for (int nf = 0; nf < 4; ++nf) {
      const int cg = bn + wc * 64 + nf * 16 + lr4;  // output col, %4==0
      if (MODE == 1) {
        u16x4 o;
#pragma unroll
        for (int j = 0; j < 4; ++j) o[j] = f2bf(acc[mf][nf][j]);
        *(u16x4*)&Cb[((long)((bi * 8 + (cg >> 6)) * 4096 + s)) * 64 +
                     (cg & 63)] = o;
      } else {
        float4 o;
        o.x = acc[mf][nf][0]; o.y = acc[mf][nf][1];
        o.z = acc[mf][nf][2]; o.w = acc[mf][nf][3];
        *(float4*)&Cf[(long)r * DM + cg] = o;
      }
    }
  }
}

// ---------------------------------------------------------------------------
// MFMA local attention (R3 version, proven 43.9 us). grid (32,8,2) x 256.
// ---------------------------------------------------------------------------
__global__ __launch_bounds__(256, 2) void attn_mfma(
    const u16* __restrict__ qg, const u16* __restrict__ kgl,
    const u16* __restrict__ vgl, const u16* __restrict__ relb,
    u16* __restrict__ pre) {
  const int n = blockIdx.x, hh = blockIdx.y, b = blockIdx.z;
  const int tid = threadIdx.x;
  const int lane = tid & 63, w = tid >> 6;
  const int g = lane >> 4, lc = lane & 15;

  __shared__ u16 Ks[64 * 72];
  __shared__ u16 Vt[64 * 72];
  __shared__ u16 Pl[4][32 * 72];
  __shared__ u16 qrelL[128 * 132];

  const size_t bh = (size_t)(b * NH + hh);

  const u16* qbase = qg + (bh * S_LEN + (size_t)n * 128 + w * 32) * HD;
  bf16x8 qf[2][2];
#pragma unroll
  for (int qt = 0; qt < 2; ++qt)
#pragma unroll
    for (int dc = 0; dc < 2; ++dc)
      qf[qt][dc] =
          *(const bf16x8*)(qbase + (lc + 16 * qt) * HD + g * 8 + 32 * dc);

  const u16* rh = relb + (size_t)hh * (144 * 64);
#pragma unroll
  for (int rt = 0; rt < 9; ++rt) {
    f32x4 acc[2] = {{0.f, 0.f, 0.f, 0.f}, {0.f, 0.f, 0.f, 0.f}};
#pragma unroll
    for (int dc = 0; dc < 2; ++dc) {
      const bf16x8 rf =
          *(const bf16x8*)(rh + (lc + 16 * rt) * 64 + g * 8 + 32 * dc);
#pragma unroll
      for (int qt = 0; qt < 2; ++qt)
        acc[qt] = __builtin_amdgcn_mfma_f32_16x16x32_bf16(qf[qt][dc], rf,
                                                          acc[qt], 0, 0, 0);
    }
#pragma unroll
    for (int qt = 0; qt < 2; ++qt)
#pragma unroll
      for (int jj = 0; jj < 4; ++jj)
        qrelL[(w * 32 + qt * 16 + g * 4 + jj) * 132 + lc + 16 * rt] =
            f2bf(acc[qt][jj]);
  }

  float m_r[2][4], l_r[2][4];
  f32x4 Oa[2][4];
#pragma unroll
  for (int qt = 0; qt < 2; ++qt)
#pragma unroll
    for (int jj = 0; jj < 4; ++jj) {
      m_r[qt][jj] = -1e30f;
      l_r[qt][jj] = 0.f;
    }
#pragma unroll
  for (int qt = 0; qt < 2; ++qt)
#pragma unroll
    for (int dt = 0; dt < 4; ++dt) Oa[qt][dt] = f32x4{0.f, 0.f, 0.f, 0.f};

  const u16* kbase = kgl + bh * S_LEN * HD;
  const u16* vbase = vgl + bh * S_LEN * HD;
  const int sk = tid & 63;
  const int sd = (tid >> 6) * 16;

  const int t0 = (n == 0) ? 2 : 0;
  const int t1 = (n == NB - 1) ? 4 : 6;

  for (int t = t0; t < t1; ++t) {
    {
      const int kglob = n * 128 - 128 + t * 64 + sk;
      const int kc = min(max(kglob, 0), S_LEN - 1);
      const u16* krow = kbase + (size_t)kc * HD + sd;
      const u16* vrow = vbase + (size_t)kc * HD + sd;
      const u16x8 ka = *(const u16x8*)krow;
      const u16x8 kb2 = *(const u16x8*)(krow + 8);
      const u16x8 va = *(const u16x8*)vrow;
      const u16x8 vb2 = *(const u16x8*)(vrow + 8);
      *(u16x8*)&Ks[sk * 72 + sd] = ka;
      *(u16x8*)&Ks[sk * 72 + sd + 8] = kb2;
#pragma unroll
      for (int e = 0; e < 8; ++e) {
        Vt[(sd + e) * 72 + sk] = va[e];
        Vt[(sd + 8 + e) * 72 + sk] = vb2[e];
      }
    }
    __syncthreads();

    f32x4 E[2][4];
#pragma unroll
    for (int qt = 0; qt < 2; ++qt)
#pragma unroll
      for (int kt = 0; kt < 4; ++kt) E[qt][kt] = f32x4{0.f, 0.f, 0.f, 0.f};
#pragma unroll
    for (int kt = 0; kt < 4; ++kt)
#pragma unroll
      for (int dc = 0; dc < 2; ++dc) {
        const bf16x8 kf =
            *(const bf16x8*)&Ks[(lc + 16 * kt) * 72 + g * 8 + 32 * dc];
#pragma unroll
        for (int qt = 0; qt < 2; ++qt)
          E[qt][kt] = __builtin_amdgcn_mfma_f32_16x16x32_bf16(
              qf[qt][dc], kf, E[qt][kt], 0, 0, 0);
      }

#pragma unroll
    for (int qt = 0; qt < 2; ++qt)
#pragma unroll
      for (int jj = 0; jj < 4; ++jj) {
        const int q = w * 32 + qt * 16 + g * 4 + jj;
#pragma unroll
        for (int kt = 0; kt < 4; ++kt) {
          const int j = t * 64 + kt * 16 + lc;
          const int dpos = j - 128 - q;
          const int kglob = n * 128 - 128 + j;
          const int idc = min(max(dpos, -64), 64) + 64;
          const float bias = bf2f(qrelL[q * 132 + idc]);
          const float e = E[qt][kt][jj] + bias;
          const bool bad = (dpos > 127) || (dpos < -127) ||
                           ((unsigned)kglob >= (unsigned)S_LEN);
          E[qt][kt][jj] = bad ? -1e30f : e;
        }
      }

#pragma unroll
    for (int qt = 0; qt < 2; ++qt)
#pragma unroll
      for (int jj = 0; jj < 4; ++jj) {
        float mx = fmaxf(fmaxf(E[qt][0][jj], E[qt][1][jj]),
                         fmaxf(E[qt][2][jj], E[qt][3][jj]));
        mx = fmaxf(mx, __shfl_xor(mx, 1));
        mx = fmaxf(mx, __shfl_xor(mx, 2));
        mx = fmaxf(mx, __shfl_xor(mx, 4));
        mx = fmaxf(mx, __shfl_xor(mx, 8));
        const float nm = fmaxf(m_r[qt][jj], mx);
        const float sc = __expf(m_r[qt][jj] - nm);
        m_r[qt][jj] = nm;
        l_r[qt][jj] *= sc;
#pragma unroll
        for (int dt = 0; dt < 4; ++dt) Oa[qt][dt][jj] *= sc;
        float ps = 0.f;
#pragma unroll
        for (int kt = 0; kt < 4; ++kt) {
          const float p = __expf(E[qt][kt][jj] - nm);
          ps += p;
          Pl[w][(qt * 16 + g * 4 + jj) * 72 + lc + 16 * kt] = f2bf(p);
        }
        ps += __shfl_xor(ps, 1);
        ps += __shfl_xor(ps, 2);
        ps += __shfl_xor(ps, 4);
        ps += __shfl_xor(ps, 8);
        l_r[qt][jj] += ps;
      }
    __syncthreads();

#pragma unroll
    for (int c = 0; c < 2; ++c) {
      bf16x8 pf[2];
#pragma unroll
      for (int qt = 0; qt < 2; ++qt)
        pf[qt] = *(const bf16x8*)&Pl[w][(lc + 16 * qt) * 72 + g * 8 + 32 * c];
#pragma unroll
      for (int dt = 0; dt < 4; ++dt) {
        const bf16x8 vf =
            *(const bf16x8*)&Vt[(lc + 16 * dt) * 72 + g * 8 + 32 * c];
#pragma unroll
        for (int qt = 0; qt < 2; ++qt)
          Oa[qt][dt] = __builtin_amdgcn_mfma_f32_16x16x32_bf16(
              pf[qt], vf, Oa[qt][dt], 0, 0, 0);
      }
    }
    __syncthreads();
  }

  u16* prow = pre + (bh * S_LEN + (size_t)n * 128 + w * 32) * HD;
#pragma unroll
  for (int qt = 0; qt < 2; ++qt)
#pragma unroll
    for (int jj = 0; jj < 4; ++jj) {
      const float inv = 1.f / l_r[qt][jj];
      const int row = qt * 16 + g * 4 + jj;
#pragma unroll
      for (int dt = 0; dt < 4; ++dt)
        prow[row * HD + lc + 16 * dt] = f2bf(Oa[qt][dt][jj] * inv);
    }
}

// ---------------------------------------------------------------------------
extern "C" void kernel_launch(void* const* d_in, const int* in_sizes, int n_in,
                              void* d_out, int out_size, void* d_ws,
                              size_t ws_size, hipStream_t stream) {
  const float* Q = (const float*)d_in[0];
  const float* K = (const float*)d_in[1];
  const float* V = (const float*)d_in[2];
  const float* Wq = (const float*)d_in[4];
  const float* Wk = (const float*)d_in[5];
  const float* Wv = (const float*)d_in[6];
  const float* Wo = (const float*)d_in[7];
  const float* rel = (const float*)d_in[8];
  float* out = (float*)d_out;

  const size_t NE = 4194304;  // 2*8*4096*64
  u16* ws16 = (u16*)d_ws;
  u16* qb = ws16;
  u16* kb = qb + NE;
  u16* vb = kb + NE;
  u16* pre = vb + NE;
  u16* WqT = pre + NE;
  u16* WkT = WqT + 262144;
  u16* WvT = WkT + 262144;
  u16* WoT = WvT + 262144;
  u16* relb = WoT + 262144;  // 8*144*64

  conv_w<<<dim3(256, 4), 256, 0, stream>>>(Wq, Wk, Wv, Wo, WqT, WkT, WvT, WoT);
  conv_rel<<<dim3(129), 128, 0, stream>>>(rel, relb);
  gemm_bf16<1><<<dim3(128, 4, 3), 256, 0, stream>>>(
      Q, K, V, nullptr, WqT, WkT, WvT, qb, kb, vb, nullptr);
  attn_mfma<<<dim3(NB, NH, 2), 256, 0, stream>>>(qb, kb, vb, relb, pre);
  gemm_bf16<2><<<dim3(128, 4, 1), 256, 0, stream>>>(
      nullptr, nullptr, nullptr, pre, WoT, nullptr, nullptr, nullptr, nullptr,
      nullptr, out);
}

// Round 9
// 192.342 us; speedup vs baseline: 1.0056x; 1.0056x over previous
//
#include <hip/hip_runtime.h>
#include <hip/hip_bf16.h>

typedef unsigned short u16;
typedef __bf16 bf16_t;
typedef bf16_t bf16x8 __attribute__((ext_vector_type(8)));
typedef float f32x4 __attribute__((ext_vector_type(4)));
typedef u16 u16x4 __attribute__((ext_vector_type(4)));
typedef u16 u16x8 __attribute__((ext_vector_type(8)));

#define S_LEN 4096
#define NH 8
#define HD 64
#define DM 512
#define NB 32

__device__ __forceinline__ u16 f2bf(float f) {
  unsigned int u = __builtin_bit_cast(unsigned int, f);
  u = (u + 0x7fff + ((u >> 16) & 1)) >> 16;  // RNE
  return (u16)u;
}
__device__ __forceinline__ float bf2f(u16 h) {
  unsigned int u = ((unsigned int)h) << 16;
  return __builtin_bit_cast(float, u);
}

#define GLDS16(gaddr, laddr)                                                  \
  __builtin_amdgcn_global_load_lds(                                           \
      (const __attribute__((address_space(1))) unsigned int*)(gaddr),         \
      (__attribute__((address_space(3))) unsigned int*)(laddr), 16, 0, 0)

// ---------------------------------------------------------------------------
// Weights: fp32 [K][N] -> bf16 [N][K] via coalesced LDS tile transpose.
// Wq scaled 1/8 (folds 1/sqrt(hd)); Wo source-row-permuted
// (srow = (k&63)*8 + (k>>6)) to fold transpose(0,2,3,1). grid (64,4) x 256.
// ---------------------------------------------------------------------------
__global__ __launch_bounds__(256) void conv_w(
    const float* __restrict__ Wq, const float* __restrict__ Wk,
    const float* __restrict__ Wv, const float* __restrict__ Wo,
    u16* __restrict__ WqT, u16* __restrict__ WkT, u16* __restrict__ WvT,
    u16* __restrict__ WoT) {
  const int z = blockIdx.y;
  const float* src = z == 0 ? Wq : (z == 1 ? Wk : (z == 2 ? Wv : Wo));
  u16* dst = z == 0 ? WqT : (z == 1 ? WkT : (z == 2 ? WvT : WoT));
  const float scl = (z == 0) ? 0.125f : 1.f;
  const int k0 = (blockIdx.x >> 3) * 64;
  const int n0 = (blockIdx.x & 7) * 64;

  __shared__ u16 T[64][68];
  const int rr = threadIdx.x >> 4;        // 0..15
  const int c4 = (threadIdx.x & 15) * 4;  // 0..60

#pragma unroll
  for (int p = 0; p < 4; ++p) {
    const int r = p * 16 + rr;  // k within tile
    const int k = k0 + r;
    const int srow = (z == 3) ? ((k & 63) * 8 + (k >> 6)) : k;
    const float4 v = *(const float4*)&src[srow * DM + n0 + c4];
    u16x4 o;
    o[0] = f2bf(v.x * scl); o[1] = f2bf(v.y * scl);
    o[2] = f2bf(v.z * scl); o[3] = f2bf(v.w * scl);
    *(u16x4*)&T[r][c4] = o;
  }
  __syncthreads();
#pragma unroll
  for (int p = 0; p < 4; ++p) {
    const int nn = p * 16 + rr;  // n within tile
    u16x4 o;
#pragma unroll
    for (int j = 0; j < 4; ++j) o[j] = T[c4 + j][nn];
    *(u16x4*)&dst[(n0 + nn) * DM + k0 + c4] = o;
  }
}

// ---------------------------------------------------------------------------
// rel_emb fp32 [8][129][64] -> bf16 [8][144][64] (row-padded; pad rows never
// read: idc <= 128). grid 129 x 128.
// ---------------------------------------------------------------------------
__global__ __launch_bounds__(128) void conv_rel(const float* __restrict__ rel,
                                                u16* __restrict__ relb) {
  const int e = (blockIdx.x * 128 + threadIdx.x) * 4;
  const int h = e / (129 * 64);
  const int rem = e - h * (129 * 64);
  const float4 v = *(const float4*)(rel + e);
  u16x4 o;
  o[0] = f2bf(v.x); o[1] = f2bf(v.y); o[2] = f2bf(v.z); o[3] = f2bf(v.w);
  *(u16x4*)(relb + (size_t)h * (144 * 64) + rem) = o;
}

// ---------------------------------------------------------------------------
// bf16 MFMA GEMM, 64x128 tile, BK=32, 4 waves (each 32x64).
// T3+T4 pipeline: 3 LDS buffers, all operands via global_load_lds, raw
// s_barrier + counted vmcnt (one stage left in flight, never 0 mid-loop).
// Per iter: {wait own vmcnt(SV) -> barrier -> issue stage(t+2) -> compute(t)}.
// Write-after-barrier avoids the WAR race; wait-before-barrier guarantees
// all waves' stage(t) LDS writes landed.
// MODE 1: A = raw fp32 (Q/K/V) staged AS FP32, converted to bf16 at
//         fragment read (v_cvt_pk_bf16_f32); C scattered bf16 to (b,h,s,d).
// MODE 2: A = attn-out bf16 in (b,h,s,d); C fp32 row-major.
// MFMA operands swapped (D = C^T) for vectorized epilogue.
// ---------------------------------------------------------------------------
template <int MODE>
__global__ __launch_bounds__(256, 3) void gemm_bf16(
    const float* __restrict__ Af0, const float* __restrict__ Af1,
    const float* __restrict__ Af2, const u16* __restrict__ Ab,
    const u16* __restrict__ B0, const u16* __restrict__ B1,
    const u16* __restrict__ B2, u16* __restrict__ C0, u16* __restrict__ C1,
    u16* __restrict__ C2, float* __restrict__ Cf) {
  constexpr int ABYTES = (MODE == 1) ? 64 * 32 * 4 : 64 * 32 * 2;
  __shared__ __align__(16) unsigned char AsRaw[3][ABYTES];
  __shared__ __align__(16) u16 Bs[3][128 * 32];

  const int z = blockIdx.z;
  const float* Af = (MODE == 1) ? (z == 0 ? Af0 : (z == 1 ? Af1 : Af2)) : 0;
  const u16* Bt = (MODE == 1) ? (z == 0 ? B0 : (z == 1 ? B1 : B2)) : B0;
  u16* Cb = (MODE == 1) ? (z == 0 ? C0 : (z == 1 ? C1 : C2)) : (u16*)0;

  const int tid = threadIdx.x;
  const int lane = tid & 63;
  const int w = tid >> 6;
  const int bm = blockIdx.x * 64;
  const int bn = blockIdx.y * 128;

  f32x4 acc[2][4];
#pragma unroll
  for (int mf = 0; mf < 2; ++mf)
#pragma unroll
    for (int nf = 0; nf < 4; ++nf) acc[mf][nf] = f32x4{0.f, 0.f, 0.f, 0.f};

  const int wr = w >> 1, wc = w & 1;
  const int lrow = lane & 15;
  const int lk = (lane >> 4) * 8;

  // stage: per wave MODE1 = 4 GLDS (2 A-fp32 + 2 B), MODE2 = 3 (1 A + 2 B)
  auto stage = [&](int buf, int k0) {
    if constexpr (MODE == 1) {
#pragma unroll
      for (int t = 0; t < 2; ++t) {
        const int c = w * 2 + t;  // 8 chunks of 1KB each
        // A fp32 [64][32]: chunk rows c*8 + (lane>>3), cols (lane&7)*4
        GLDS16(Af + (long)(bm + c * 8 + (lane >> 3)) * DM + k0 + (lane & 7) * 4,
               (float*)AsRaw[buf] + c * 256);
        // B bf16 [128][32]: chunk rows c*16 + (lane>>2), cols (lane&3)*8
        GLDS16(Bt + (long)(bn + c * 16 + (lane >> 2)) * DM + k0 + (lane & 3) * 8,
               &Bs[buf][c * 512]);
      }
    } else {
      {
        const int c = w;  // A bf16 [64][32]: 4 chunks
        const int r = bm + c * 16 + (lane >> 2);
        const int b = r >> 12, s = r & 4095;
        const int k = k0 + (lane & 3) * 8;
        GLDS16(Ab + ((long)((b * 8 + (k >> 6)) * 4096 + s)) * 64 + (k & 63),
               (u16*)AsRaw[buf] + c * 512);
      }
#pragma unroll
      for (int t = 0; t < 2; ++t) {
        const int c = w * 2 + t;
        GLDS16(Bt + (long)(bn + c * 16 + (lane >> 2)) * DM + k0 + (lane & 3) * 8,
               &Bs[buf][c * 512]);
      }
    }
  };

  auto loadA = [&](int cur, int mf) -> bf16x8 {
    if constexpr (MODE == 1) {
      const float* p =
          (const float*)AsRaw[cur] + (wr * 32 + mf * 16 + lrow) * 32 + lk;
      const float4 a0 = *(const float4*)p;
      const float4 a1 = *(const float4*)(p + 4);
      unsigned int w0, w1, w2, w3;
      asm("v_cvt_pk_bf16_f32 %0, %1, %2" : "=v"(w0) : "v"(a0.x), "v"(a0.y));
      asm("v_cvt_pk_bf16_f32 %0, %1, %2" : "=v"(w1) : "v"(a0.z), "v"(a0.w));
      asm("v_cvt_pk_bf16_f32 %0, %1, %2" : "=v"(w2) : "v"(a1.x), "v"(a1.y));
      asm("v_cvt_pk_bf16_f32 %0, %1, %2" : "=v"(w3) : "v"(a1.z), "v"(a1.w));
      union { unsigned int u[4]; bf16x8 v; } r;
      r.u[0] = w0; r.u[1] = w1; r.u[2] = w2; r.u[3] = w3;
      return r.v;
    } else {
      return *(const bf16x8*)((const u16*)AsRaw[cur] +
                              (wr * 32 + mf * 16 + lrow) * 32 + lk);
    }
  };

  auto compute = [&](int cur) {
    bf16x8 af[2], bfr[4];
#pragma unroll
    for (int mf = 0; mf < 2; ++mf) af[mf] = loadA(cur, mf);
#pragma unroll
    for (int nf = 0; nf < 4; ++nf)
      bfr[nf] = *(const bf16x8*)&Bs[cur][(wc * 64 + nf * 16 + lrow) * 32 + lk];
#pragma unroll
    for (int mf = 0; mf < 2; ++mf)
#pragma unroll
      for (int nf = 0; nf < 4; ++nf)
        acc[mf][nf] = __builtin_amdgcn_mfma_f32_16x16x32_bf16(
            bfr[nf], af[mf], acc[mf][nf], 0, 0, 0);  // swapped: D = C^T
  };

  stage(0, 0);
  stage(1, 32);
  for (int t = 0; t < 16; ++t) {
    if (t < 15) {
      if constexpr (MODE == 1)
        asm volatile("s_waitcnt vmcnt(4)" ::: "memory");
      else
        asm volatile("s_waitcnt vmcnt(3)" ::: "memory");
    } else {
      asm volatile("s_waitcnt vmcnt(0)" ::: "memory");
    }
    __builtin_amdgcn_s_barrier();
    __builtin_amdgcn_sched_barrier(0);
    if (t < 14) stage((t + 2) % 3, (t + 2) * 32);
    compute(t % 3);
  }

  // epilogue: D row = n-dim (lr4+j), col = m-dim (lc)
  const int lr4 = (lane >> 4) * 4;
  const int lc = lane & 15;
#pragma unroll
  for (int mf = 0; mf < 2; ++mf) {
    const int r = bm + wr * 32 + mf * 16 + lc;  // output row (s-dim)
    const int bi = r >> 12, s = r & 4095;
#pragma unroll
    for (int nf = 0; nf < 4; ++nf) {
      const int cg = bn + wc * 64 + nf * 16 + lr4;  // output col, %4==0
      if (MODE == 1) {
        u16x4 o;
#pragma unroll
        for (int j = 0; j < 4; ++j) o[j] = f2bf(acc[mf][nf][j]);
        *(u16x4*)&Cb[((long)((bi * 8 + (cg >> 6)) * 4096 + s)) * 64 +
                     (cg & 63)] = o;
      } else {
        float4 o;
        o.x = acc[mf][nf][0]; o.y = acc[mf][nf][1];
        o.z = acc[mf][nf][2]; o.w = acc[mf][nf][3];
        *(float4*)&Cf[(long)r * DM + cg] = o;
      }
    }
  }
}

// ---------------------------------------------------------------------------
// MFMA local attention (R3 version, proven 43.9 us). grid (32,8,2) x 256.
// ---------------------------------------------------------------------------
__global__ __launch_bounds__(256, 2) void attn_mfma(
    const u16* __restrict__ qg, const u16* __restrict__ kgl,
    const u16* __restrict__ vgl, const u16* __restrict__ relb,
    u16* __restrict__ pre) {
  const int n = blockIdx.x, hh = blockIdx.y, b = blockIdx.z;
  const int tid = threadIdx.x;
  const int lane = tid & 63, w = tid >> 6;
  const int g = lane >> 4, lc = lane & 15;

  __shared__ u16 Ks[64 * 72];
  __shared__ u16 Vt[64 * 72];
  __shared__ u16 Pl[4][32 * 72];
  __shared__ u16 qrelL[128 * 132];

  const size_t bh = (size_t)(b * NH + hh);

  const u16* qbase = qg + (bh * S_LEN + (size_t)n * 128 + w * 32) * HD;
  bf16x8 qf[2][2];
#pragma unroll
  for (int qt = 0; qt < 2; ++qt)
#pragma unroll
    for (int dc = 0; dc < 2; ++dc)
      qf[qt][dc] =
          *(const bf16x8*)(qbase + (lc + 16 * qt) * HD + g * 8 + 32 * dc);

  const u16* rh = relb + (size_t)hh * (144 * 64);
#pragma unroll
  for (int rt = 0; rt < 9; ++rt) {
    f32x4 acc[2] = {{0.f, 0.f, 0.f, 0.f}, {0.f, 0.f, 0.f, 0.f}};
#pragma unroll
    for (int dc = 0; dc < 2; ++dc) {
      const bf16x8 rf =
          *(const bf16x8*)(rh + (lc + 16 * rt) * 64 + g * 8 + 32 * dc);
#pragma unroll
      for (int qt = 0; qt < 2; ++qt)
        acc[qt] = __builtin_amdgcn_mfma_f32_16x16x32_bf16(qf[qt][dc], rf,
                                                          acc[qt], 0, 0, 0);
    }
#pragma unroll
    for (int qt = 0; qt < 2; ++qt)
#pragma unroll
      for (int jj = 0; jj < 4; ++jj)
        qrelL[(w * 32 + qt * 16 + g * 4 + jj) * 132 + lc + 16 * rt] =
            f2bf(acc[qt][jj]);
  }

  float m_r[2][4], l_r[2][4];
  f32x4 Oa[2][4];
#pragma unroll
  for (int qt = 0; qt < 2; ++qt)
#pragma unroll
    for (int jj = 0; jj < 4; ++jj) {
      m_r[qt][jj] = -1e30f;
      l_r[qt][jj] = 0.f;
    }
#pragma unroll
  for (int qt = 0; qt < 2; ++qt)
#pragma unroll
    for (int dt = 0; dt < 4; ++dt) Oa[qt][dt] = f32x4{0.f, 0.f, 0.f, 0.f};

  const u16* kbase = kgl + bh * S_LEN * HD;
  const u16* vbase = vgl + bh * S_LEN * HD;
  const int sk = tid & 63;
  const int sd = (tid >> 6) * 16;

  const int t0 = (n == 0) ? 2 : 0;
  const int t1 = (n == NB - 1) ? 4 : 6;

  for (int t = t0; t < t1; ++t) {
    {
      const int kglob = n * 128 - 128 + t * 64 + sk;
      const int kc = min(max(kglob, 0), S_LEN - 1);
      const u16* krow = kbase + (size_t)kc * HD + sd;
      const u16* vrow = vbase + (size_t)kc * HD + sd;
      const u16x8 ka = *(const u16x8*)krow;
      const u16x8 kb2 = *(const u16x8*)(krow + 8);
      const u16x8 va = *(const u16x8*)vrow;
      const u16x8 vb2 = *(const u16x8*)(vrow + 8);
      *(u16x8*)&Ks[sk * 72 + sd] = ka;
      *(u16x8*)&Ks[sk * 72 + sd + 8] = kb2;
#pragma unroll
      for (int e = 0; e < 8; ++e) {
        Vt[(sd + e) * 72 + sk] = va[e];
        Vt[(sd + 8 + e) * 72 + sk] = vb2[e];
      }
    }
    __syncthreads();

    f32x4 E[2][4];
#pragma unroll
    for (int qt = 0; qt < 2; ++qt)
#pragma unroll
      for (int kt = 0; kt < 4; ++kt) E[qt][kt] = f32x4{0.f, 0.f, 0.f, 0.f};
#pragma unroll
    for (int kt = 0; kt < 4; ++kt)
#pragma unroll
      for (int dc = 0; dc < 2; ++dc) {
        const bf16x8 kf =
            *(const bf16x8*)&Ks[(lc + 16 * kt) * 72 + g * 8 + 32 * dc];
#pragma unroll
        for (int qt = 0; qt < 2; ++qt)
          E[qt][kt] = __builtin_amdgcn_mfma_f32_16x16x32_bf16(
              qf[qt][dc], kf, E[qt][kt], 0, 0, 0);
      }

#pragma unroll
    for (int qt = 0; qt < 2; ++qt)
#pragma unroll
      for (int jj = 0; jj < 4; ++jj) {
        const int q = w * 32 + qt * 16 + g * 4 + jj;
#pragma unroll
        for (int kt = 0; kt < 4; ++kt) {
          const int j = t * 64 + kt * 16 + lc;
          const int dpos = j - 128 - q;
          const int kglob = n * 128 - 128 + j;
          const int idc = min(max(dpos, -64), 64) + 64;
          const float bias = bf2f(qrelL[q * 132 + idc]);
          const float e = E[qt][kt][jj] + bias;
          const bool bad = (dpos > 127) || (dpos < -127) ||
                           ((unsigned)kglob >= (unsigned)S_LEN);
          E[qt][kt][jj] = bad ? -1e30f : e;
        }
      }

#pragma unroll
    for (int qt = 0; qt < 2; ++qt)
#pragma unroll
      for (int jj = 0; jj < 4; ++jj) {
        float mx = fmaxf(fmaxf(E[qt][0][jj], E[qt][1][jj]),
                         fmaxf(E[qt][2][jj], E[qt][3][jj]));
        mx = fmaxf(mx, __shfl_xor(mx, 1));
        mx = fmaxf(mx, __shfl_xor(mx, 2));
        mx = fmaxf(mx, __shfl_xor(mx, 4));
        mx = fmaxf(mx, __shfl_xor(mx, 8));
        const float nm = fmaxf(m_r[qt][jj], mx);
        const float sc = __expf(m_r[qt][jj] - nm);
        m_r[qt][jj] = nm;
        l_r[qt][jj] *= sc;
#pragma unroll
        for (int dt = 0; dt < 4; ++dt) Oa[qt][dt][jj] *= sc;
        float ps = 0.f;
#pragma unroll
        for (int kt = 0; kt < 4; ++kt) {
          const float p = __expf(E[qt][kt][jj] - nm);
          ps += p;
          Pl[w][(qt * 16 + g * 4 + jj) * 72 + lc + 16 * kt] = f2bf(p);
        }
        ps += __shfl_xor(ps, 1);
        ps += __shfl_xor(ps, 2);
        ps += __shfl_xor(ps, 4);
        ps += __shfl_xor(ps, 8);
        l_r[qt][jj] += ps;
      }
    __syncthreads();

#pragma unroll
    for (int c = 0; c < 2; ++c) {
      bf16x8 pf[2];
#pragma unroll
      for (int qt = 0; qt < 2; ++qt)
        pf[qt] = *(const bf16x8*)&Pl[w][(lc + 16 * qt) * 72 + g * 8 + 32 * c];
#pragma unroll
      for (int dt = 0; dt < 4; ++dt) {
        const bf16x8 vf =
            *(const bf16x8*)&Vt[(lc + 16 * dt) * 72 + g * 8 + 32 * c];
#pragma unroll
        for (int qt = 0; qt < 2; ++qt)
          Oa[qt][dt] = __builtin_amdgcn_mfma_f32_16x16x32_bf16(
              pf[qt], vf, Oa[qt][dt], 0, 0, 0);
      }
    }
    __syncthreads();
  }

  u16* prow = pre + (bh * S_LEN + (size_t)n * 128 + w * 32) * HD;
#pragma unroll
  for (int qt = 0; qt < 2; ++qt)
#pragma unroll
    for (int jj = 0; jj < 4; ++jj) {
      const float inv = 1.f / l_r[qt][jj];
      const int row = qt * 16 + g * 4 + jj;
#pragma unroll
      for (int dt = 0; dt < 4; ++dt)
        prow[row * HD + lc + 16 * dt] = f2bf(Oa[qt][dt][jj] * inv);
    }
}

// ---------------------------------------------------------------------------
extern "C" void kernel_launch(void* const* d_in, const int* in_sizes, int n_in,
                              void* d_out, int out_size, void* d_ws,
                              size_t ws_size, hipStream_t stream) {
  const float* Q = (const float*)d_in[0];
  const float* K = (const float*)d_in[1];
  const float* V = (const float*)d_in[2];
  const float* Wq = (const float*)d_in[4];
  const float* Wk = (const float*)d_in[5];
  const float* Wv = (const float*)d_in[6];
  const float* Wo = (const float*)d_in[7];
  const float* rel = (const float*)d_in[8];
  float* out = (float*)d_out;

  const size_t NE = 4194304;  // 2*8*4096*64
  u16* ws16 = (u16*)d_ws;
  u16* qb = ws16;
  u16* kb = qb + NE;
  u16* vb = kb + NE;
  u16* pre = vb + NE;
  u16* WqT = pre + NE;
  u16* WkT = WqT + 262144;
  u16* WvT = WkT + 262144;
  u16* WoT = WvT + 262144;
  u16* relb = WoT + 262144;  // 8*144*64

  conv_w<<<dim3(64, 4), 256, 0, stream>>>(Wq, Wk, Wv, Wo, WqT, WkT, WvT, WoT);
  conv_rel<<<dim3(129), 128, 0, stream>>>(rel, relb);
  gemm_bf16<1><<<dim3(128, 4, 3), 256, 0, stream>>>(
      Q, K, V, nullptr, WqT, WkT, WvT, qb, kb, vb, nullptr);
  attn_mfma<<<dim3(NB, NH, 2), 256, 0, stream>>>(qb, kb, vb, relb, pre);
  gemm_bf16<2><<<dim3(128, 4, 1), 256, 0, stream>>>(
      nullptr, nullptr, nullptr, pre, WoT, nullptr, nullptr, nullptr, nullptr,
      nullptr, out);
}